// Round 7
// baseline (156.911 us; speedup 1.0000x reference)
//
#include <hip/hip_runtime.h>
#include <hip/hip_bf16.h>

#define L 2048
#define HD 1024   // H*D
#define NB 8      // batch
#define NT 32     // K tiles of BK=64
#define PROW 4096 // p8 row length

using f32x4 = __attribute__((ext_vector_type(4))) float;
using fl4   = __attribute__((ext_vector_type(4))) float;
using s16x8 = __attribute__((ext_vector_type(8))) short;

__device__ __forceinline__ short f2bf(float f) {
    __hip_bfloat16 h = __float2bfloat16(f);
    short s;
    __builtin_memcpy(&s, &h, 2);
    return s;
}

// ---- fused: p8[s][x] = bf16(p[x+s]) (blocks 0..127) ; z (block 128) ----
__global__ __launch_bounds__(256) void pb_prep(const float* __restrict__ w,
                                               short* __restrict__ p8,
                                               float* __restrict__ z) {
    __shared__ float part[256];
    __shared__ float S[L];
    const int t = threadIdx.x;
    if (blockIdx.x < 128) {
        int idx = blockIdx.x * 256 + t;
        int s = idx >> 12;
        int x = idx & (PROW - 1);
        int k = x + s;
        short val = 0;
        if (k <= 4094) {
            int d = k - 2047; d = d < 0 ? -d : d;
            val = f2bf(w[d]);
        }
        p8[idx] = val;
    } else {
        float loc[8]; float s = 0.f;
        #pragma unroll
        for (int i = 0; i < 8; ++i) { loc[i] = w[t * 8 + i]; s += loc[i]; }
        part[t] = s;
        __syncthreads();
        if (t == 0) {
            float a = 0.f;
            for (int i = 0; i < 256; ++i) { float tmp = part[i]; part[i] = a; a += tmp; }
        }
        __syncthreads();
        float a = part[t];
        #pragma unroll
        for (int i = 0; i < 8; ++i) { a += loc[i]; S[t * 8 + i] = a; }
        __syncthreads();
        const float w0 = S[0];
        #pragma unroll
        for (int i = 0; i < 8; ++i) {
            int j = t * 8 + i;
            z[j] = S[j] + S[2047 - j] - w0;
        }
    }
}

// ---- vt chunks: [n][kk][G=c>>4][h=k>>3][cl=c&15], 16B each =
//      bf16(v[n][kk*64 + h*8 + j][G*16+cl]), j=0..7 ----
__global__ __launch_bounds__(256) void pb_vtile(const float* __restrict__ v,
                                                s16x8* __restrict__ vt) {
    // Ts: (c,k) at c*64 + ((kblk ^ ((c>>2)&7))<<3) + ksub  (slot swizzle)
    __shared__ __align__(16) short Ts[256 * 64];   // 32 KB
    const int kk = blockIdx.x, cg4 = blockIdx.y, n = blockIdx.z;
    const int l0 = kk * 64, c0 = cg4 * 256;
    const int t = threadIdx.x;
    const float* vn = v + (size_t)n * L * HD;

    #pragma unroll
    for (int i = 0; i < 16; ++i) {
        int unit = i * 256 + t;          // 4096 units = 64 l x 64 quads
        int l = unit >> 6, cq = unit & 63;
        fl4 x = *(const fl4*)&vn[(size_t)(l0 + l) * HD + c0 + cq * 4];
        int lsub = l & 7, lblk = l >> 3;
        #pragma unroll
        for (int j = 0; j < 4; ++j) {
            int c = cq * 4 + j;
            Ts[c * 64 + ((lblk ^ ((c >> 2) & 7)) << 3) + lsub] = f2bf(x[j]);
        }
    }
    __syncthreads();

    s16x8* outp = vt + ((size_t)(n * NT + kk) * 64 + cg4 * 16) * 128;
    #pragma unroll
    for (int i2 = 0; i2 < 8; ++i2) {
        int ci = i2 * 256 + t;           // Gl*128 + h*16 + cl
        int Gl = ci >> 7, h = (ci >> 4) & 7, cl = ci & 15;
        int c = Gl * 16 + cl;
        int slot = h ^ ((c >> 2) & 7);
        outp[ci] = *(const s16x8*)&Ts[c * 64 + slot * 8];
    }
}

// ---- main GEMM: 128x128/block, 4 waves, NO LDS, NO barriers ----
// A fragments gathered from p8 (L1-resident 64 KB table);
// B fragments are lane-linear 1 KB loads from the re-laid-out vt.
__global__ __launch_bounds__(256, 2) void pb_gemmr(const short* __restrict__ p8,
                                                   const s16x8* __restrict__ vt,
                                                   float* __restrict__ out) {
    const int bid = blockIdx.x;
    // XCD affinity: cm = bid%8; co-resident blocks (bid, bid+256) share (n,cm)
    const int cm = bid & 7;
    const int n  = (bid >> 3) & 7;
    const int jm = bid >> 6;
    const int j0 = jm * 128;
    const int c0 = cm * 128;

    const int t = threadIdx.x;
    const int lane = t & 63;
    const int w = t >> 6;                 // wave 0..3
    const int wr = w >> 1, wc = w & 1;    // 2x2 wave grid, 64x64 tile each
    const int fr = lane & 15, fk = lane >> 4;

    // A gather offsets into p8 (advance +64 elems per tile; srow invariant)
    int aoff[4][2];
    #pragma unroll
    for (int m = 0; m < 4; ++m)
        #pragma unroll
        for (int ki = 0; ki < 2; ++ki) {
            int r = wr * 64 + m * 16 + fr;
            int idx0 = 2047 + ki * 32 + fk * 8 - j0 - r;   // T=0
            int srow = idx0 & 7;
            aoff[m][ki] = srow * PROW + (idx0 - srow);
        }

    // B base chunk: ((n*NT+T)*64 + G)*128 + ki*64 + lane, G = cm*8 + wc*4 + nf
    const int bB = (n * NT * 64 + cm * 8 + wc * 4) * 128 + lane;

    f32x4 acc[4][4] = {};

    #pragma unroll 2
    for (int T = 0; T < NT; ++T) {
        s16x8 af[4][2], bf[4][2];
        #pragma unroll
        for (int m = 0; m < 4; ++m)
            #pragma unroll
            for (int ki = 0; ki < 2; ++ki)
                af[m][ki] = *(const s16x8*)(p8 + (aoff[m][ki] + T * 64));
        #pragma unroll
        for (int nf = 0; nf < 4; ++nf)
            #pragma unroll
            for (int ki = 0; ki < 2; ++ki)
                bf[nf][ki] = vt[bB + T * 8192 + nf * 128 + ki * 64];

        __builtin_amdgcn_s_setprio(1);
        #pragma unroll
        for (int m = 0; m < 4; ++m)
            #pragma unroll
            for (int nf = 0; nf < 4; ++nf)
                #pragma unroll
                for (int ki = 0; ki < 2; ++ki)
                    acc[m][nf] = __builtin_amdgcn_mfma_f32_16x16x32_bf16(
                        af[m][ki], bf[nf][ki], acc[m][nf], 0, 0, 0);
        __builtin_amdgcn_s_setprio(0);
    }

    // ---- epilogue: C/D layout col=lane&15, row=(lane>>4)*4+r ----
    float* outn = out + (size_t)n * L * HD;
    #pragma unroll
    for (int m = 0; m < 4; ++m) {
        const int row = j0 + wr * 64 + m * 16 + fk * 4;
        #pragma unroll
        for (int nf = 0; nf < 4; ++nf) {
            const int col = c0 + wc * 64 + nf * 16 + fr;
            #pragma unroll
            for (int r = 0; r < 4; ++r)
                outn[(size_t)(row + r) * HD + col] = acc[m][nf][r];
        }
    }
}

extern "C" void kernel_launch(void* const* d_in, const int* in_sizes, int n_in,
                              void* d_out, int out_size, void* d_ws, size_t ws_size,
                              hipStream_t stream) {
    const float* v = (const float*)d_in[0];
    const float* w = (const float*)d_in[1];
    float* out = (float*)d_out;

    short* p8 = (short*)d_ws;                          // 64 KB
    s16x8* vt = (s16x8*)((char*)d_ws + 65536);         // 32 MB

    pb_prep<<<129, 256, 0, stream>>>(w, p8, out + (size_t)NB * L * HD);
    pb_vtile<<<dim3(NT, 4, NB), 256, 0, stream>>>(v, vt);
    pb_gemmr<<<1024, 256, 0, stream>>>(p8, vt, out);
}

// Round 8
// 81.908 us; speedup vs baseline: 1.9157x; 1.9157x over previous
//
#include <hip/hip_runtime.h>
#include <hip/hip_bf16.h>

#define L 2048
#define HD 1024   // H*D
#define NB 8      // batch
#define NT 32     // K tiles of BK=64
#define PROW 4096 // p8 row length

using f32x4 = __attribute__((ext_vector_type(4))) float;
using fl4   = __attribute__((ext_vector_type(4))) float;
using s16x8 = __attribute__((ext_vector_type(8))) short;

__device__ __forceinline__ short f2bf(float f) {
    __hip_bfloat16 h = __float2bfloat16(f);
    short s;
    __builtin_memcpy(&s, &h, 2);
    return s;
}

__device__ __forceinline__ void gload_lds16(const void* g, void* l) {
    __builtin_amdgcn_global_load_lds(
        (const __attribute__((address_space(1))) unsigned int*)g,
        (__attribute__((address_space(3))) unsigned int*)l, 16, 0, 0);
}

// ---- fused: p8[s][x] = bf16(p[x+s]) (blocks 0..127) ; z (block 128) ----
__global__ __launch_bounds__(256) void pb_prep(const float* __restrict__ w,
                                               short* __restrict__ p8,
                                               float* __restrict__ z) {
    __shared__ float part[256];
    __shared__ float S[L];
    const int t = threadIdx.x;
    if (blockIdx.x < 128) {
        int idx = blockIdx.x * 256 + t;
        int s = idx >> 12;
        int x = idx & (PROW - 1);
        int k = x + s;
        short val = 0;
        if (k <= 4094) {
            int d = k - 2047; d = d < 0 ? -d : d;
            val = f2bf(w[d]);
        }
        p8[idx] = val;
    } else {
        float loc[8]; float s = 0.f;
        #pragma unroll
        for (int i = 0; i < 8; ++i) { loc[i] = w[t * 8 + i]; s += loc[i]; }
        part[t] = s;
        __syncthreads();
        if (t == 0) {
            float a = 0.f;
            for (int i = 0; i < 256; ++i) { float tmp = part[i]; part[i] = a; a += tmp; }
        }
        __syncthreads();
        float a = part[t];
        #pragma unroll
        for (int i = 0; i < 8; ++i) { a += loc[i]; S[t * 8 + i] = a; }
        __syncthreads();
        const float w0 = S[0];
        #pragma unroll
        for (int i = 0; i < 8; ++i) {
            int j = t * 8 + i;
            z[j] = S[j] + S[2047 - j] - w0;
        }
    }
}

// ---- vt: linear chunk layout. chunk[((n*NT+kk)*1024 + c)*8 + h] (16B) =
//      bf16(v[n][kk*64 + h*8 + j][c]), j=0..7 ----
__global__ __launch_bounds__(256) void pb_vtile(const float* __restrict__ v,
                                                s16x8* __restrict__ vt) {
    // Ts: (c,l) at c*64 + ((lblk ^ ((c>>2)&7))<<3) + lsub  (slot swizzle)
    __shared__ __align__(16) short Ts[256 * 64];   // 32 KB
    const int kk = blockIdx.x, cg4 = blockIdx.y, n = blockIdx.z;
    const int l0 = kk * 64, c0 = cg4 * 256;
    const int t = threadIdx.x;
    const float* vn = v + (size_t)n * L * HD;

    #pragma unroll
    for (int i = 0; i < 16; ++i) {
        int unit = i * 256 + t;          // 4096 units = 64 l x 64 quads
        int l = unit >> 6, cq = unit & 63;
        fl4 x = *(const fl4*)&vn[(size_t)(l0 + l) * HD + c0 + cq * 4];
        int lsub = l & 7, lblk = l >> 3;
        #pragma unroll
        for (int j = 0; j < 4; ++j) {
            int c = cq * 4 + j;
            Ts[c * 64 + ((lblk ^ ((c >> 2) & 7)) << 3) + lsub] = f2bf(x[j]);
        }
    }
    __syncthreads();

    s16x8* outp = vt + ((size_t)(n * NT + kk) * 1024 + c0) * 8;
    #pragma unroll
    for (int i2 = 0; i2 < 8; ++i2) {
        int ci = i2 * 256 + t;           // 2048 chunks (256 c x 8 h)
        int c = ci >> 3, h = ci & 7;
        int slot = h ^ ((c >> 2) & 7);
        outp[ci] = *(const s16x8*)&Ts[c * 64 + slot * 8];
    }
}

// ---- main GEMM: 128x128 tile, BK=64, 4 waves, 2 blocks/CU,
//      register-prefetch pipeline: ds_read(T+1) overlaps MFMA(T) ----
__global__ __launch_bounds__(256, 2) void pb_gemm4(const short* __restrict__ p8,
                                                   const short* __restrict__ vt,
                                                   float* __restrict__ out) {
    __shared__ __align__(16) short lds_[32768];  // 64 KB: 2 bufs x (A 16K | B 16K)

    const int bid = blockIdx.x;
    // XCD affinity: XCD = bid%8 = cm; all 16 jm-peers of (n,cm) share one XCD
    const int cm = bid & 7;
    const int n  = (bid >> 3) & 7;
    const int jm = bid >> 6;
    const int j0 = jm * 128;
    const int c0 = cm * 128;

    const int t = threadIdx.x;
    const int lane = t & 63;
    const int w = t >> 6;                 // wave 0..3
    const int wr = w >> 1, wc = w & 1;    // 2x2 wave grid, 64x64 tile each
    const int fr = lane & 15, fk = lane >> 4;

    // K-invariant LDS read byte-offsets (ki=1 via ^64)
    int offA[4], offB[4];
    #pragma unroll
    for (int m = 0; m < 4; ++m) {
        int r = wr * 64 + m * 16 + fr;
        offA[m] = r * 128 + ((fk ^ (r & 7)) << 4);
    }
    #pragma unroll
    for (int nf = 0; nf < 4; ++nf) {
        int c = wc * 64 + nf * 16 + fr;
        offB[nf] = 16384 + c * 128 + ((fk ^ (c & 7)) << 4);
    }

    // staging sources (chunk dc = w*256 + i*64 + lane; dest byte = dc*16)
    const short* srcA0; const short* srcA1; const short* srcA2; const short* srcA3;
    const short* srcB0; const short* srcB1; const short* srcB2; const short* srcB3;
    {
        const size_t bbase = ((size_t)(n * NT) * 1024 + c0) * 8ull;
        int dc, r, s, h, q, srow, c;
        dc = w * 256 + 0 * 64 + lane;
        r = dc >> 3; s = dc & 7; h = s ^ (r & 7);
        q = 2047 + h * 8 - j0 - r; srow = q & 7;
        srcA0 = p8 + srow * PROW + (q - srow);
        c = dc >> 3; h = (dc & 7) ^ (c & 7);
        srcB0 = (const short*)(vt + (bbase + (size_t)c * 8 + h) * 8);
        dc = w * 256 + 1 * 64 + lane;
        r = dc >> 3; s = dc & 7; h = s ^ (r & 7);
        q = 2047 + h * 8 - j0 - r; srow = q & 7;
        srcA1 = p8 + srow * PROW + (q - srow);
        c = dc >> 3; h = (dc & 7) ^ (c & 7);
        srcB1 = (const short*)(vt + (bbase + (size_t)c * 8 + h) * 8);
        dc = w * 256 + 2 * 64 + lane;
        r = dc >> 3; s = dc & 7; h = s ^ (r & 7);
        q = 2047 + h * 8 - j0 - r; srow = q & 7;
        srcA2 = p8 + srow * PROW + (q - srow);
        c = dc >> 3; h = (dc & 7) ^ (c & 7);
        srcB2 = (const short*)(vt + (bbase + (size_t)c * 8 + h) * 8);
        dc = w * 256 + 3 * 64 + lane;
        r = dc >> 3; s = dc & 7; h = s ^ (r & 7);
        q = 2047 + h * 8 - j0 - r; srow = q & 7;
        srcA3 = p8 + srow * PROW + (q - srow);
        c = dc >> 3; h = (dc & 7) ^ (c & 7);
        srcB3 = (const short*)(vt + (bbase + (size_t)c * 8 + h) * 8);
    }
    const int wA = w * 4096;              // wave-uniform dest bases

#define STAGE_ALL(base) { \
    gload_lds16(srcA0, (char*)lds_ + (base) + wA); \
    gload_lds16(srcA1, (char*)lds_ + (base) + wA + 1024); \
    gload_lds16(srcA2, (char*)lds_ + (base) + wA + 2048); \
    gload_lds16(srcA3, (char*)lds_ + (base) + wA + 3072); \
    gload_lds16(srcB0, (char*)lds_ + (base) + 16384 + wA); \
    gload_lds16(srcB1, (char*)lds_ + (base) + 16384 + wA + 1024); \
    gload_lds16(srcB2, (char*)lds_ + (base) + 16384 + wA + 2048); \
    gload_lds16(srcB3, (char*)lds_ + (base) + 16384 + wA + 3072); \
    srcA0 += 64; srcA1 += 64; srcA2 += 64; srcA3 += 64; \
    srcB0 += 65536; srcB1 += 65536; srcB2 += 65536; srcB3 += 65536; }

#define VMC8()  { asm volatile("s_waitcnt vmcnt(8)" ::: "memory"); \
                  __builtin_amdgcn_sched_barrier(0); }
#define VMC0()  { asm volatile("s_waitcnt vmcnt(0)" ::: "memory"); \
                  __builtin_amdgcn_sched_barrier(0); }
#define LGKM0() { asm volatile("s_waitcnt lgkmcnt(0)" ::: "memory"); \
                  __builtin_amdgcn_sched_barrier(0); }
#define BARR()  __builtin_amdgcn_s_barrier()

#define READ_FRAGS(AF, BF, base) { \
    const char* _b = (const char*)lds_ + (base); \
    _Pragma("unroll") \
    for (int m = 0; m < 4; ++m) { \
        AF[m][0] = *(const s16x8*)(_b + offA[m]); \
        AF[m][1] = *(const s16x8*)(_b + (offA[m] ^ 64)); \
    } \
    _Pragma("unroll") \
    for (int nf = 0; nf < 4; ++nf) { \
        BF[nf][0] = *(const s16x8*)(_b + offB[nf]); \
        BF[nf][1] = *(const s16x8*)(_b + (offB[nf] ^ 64)); \
    } \
    __builtin_amdgcn_sched_barrier(0); }

#define MFMA_ALL(AF, BF) { \
    __builtin_amdgcn_s_setprio(1); \
    _Pragma("unroll") \
    for (int m = 0; m < 4; ++m) \
        _Pragma("unroll") \
        for (int nf = 0; nf < 4; ++nf) \
            _Pragma("unroll") \
            for (int ki = 0; ki < 2; ++ki) \
                acc[m][nf] = __builtin_amdgcn_mfma_f32_16x16x32_bf16( \
                    AF[m][ki], BF[nf][ki], acc[m][nf], 0, 0, 0); \
    __builtin_amdgcn_s_setprio(0); }

// body for tile T (parity P): stage T+2 into buf[P], prefetch frags(T+1)
// from buf[P^1] into NXT regs, MFMA on CUR regs (tile T).
#define BODY(P, CURA, CURB, NXTA, NXTB, DO_STAGE, VMCN) { \
    if (DO_STAGE) STAGE_ALL((P) * 32768); \
    VMCN(); \
    BARR(); \
    READ_FRAGS(NXTA, NXTB, ((P) ^ 1) * 32768); \
    MFMA_ALL(CURA, CURB); \
    LGKM0(); \
    BARR(); }

    f32x4 acc[4][4] = {};
    s16x8 afX[4][2], bfX[4][2], afY[4][2], bfY[4][2];

    // ---- prologue: stage tiles 0,1; read frags(0) into X ----
    STAGE_ALL(0);
    STAGE_ALL(32768);
    VMC8();            // tile 0 landed (tile 1's 8 loads still in flight)
    BARR();
    READ_FRAGS(afX, bfX, 0);
    LGKM0();
    BARR();            // all waves hold frags(0) -> buf0 may be overwritten

    for (int T = 0; T < NT - 2; T += 2) {
        BODY(0, afX, bfX, afY, bfY, true, VMC8);   // tile T   (even)
        BODY(1, afY, bfY, afX, bfX, true, VMC8);   // tile T+1 (odd)
    }
    // tile 30: no stage left; drain tile 31's loads fully
    BODY(0, afX, bfX, afY, bfY, false, VMC0);
    // tile 31: MFMA only
    MFMA_ALL(afY, bfY);

    // ---- epilogue: C/D layout col=lane&15, row=(lane>>4)*4+r ----
    float* outn = out + (size_t)n * L * HD;
    #pragma unroll
    for (int m = 0; m < 4; ++m) {
        const int row = j0 + wr * 64 + m * 16 + fk * 4;
        #pragma unroll
        for (int nf = 0; nf < 4; ++nf) {
            const int col = c0 + wc * 64 + nf * 16 + fr;
            #pragma unroll
            for (int r = 0; r < 4; ++r)
                outn[(size_t)(row + r) * HD + col] = acc[m][nf][r];
        }
    }
}

extern "C" void kernel_launch(void* const* d_in, const int* in_sizes, int n_in,
                              void* d_out, int out_size, void* d_ws, size_t ws_size,
                              hipStream_t stream) {
    const float* v = (const float*)d_in[0];
    const float* w = (const float*)d_in[1];
    float* out = (float*)d_out;

    short* p8 = (short*)d_ws;                          // 64 KB
    s16x8* vt = (s16x8*)((char*)d_ws + 65536);         // 32 MB

    pb_prep<<<129, 256, 0, stream>>>(w, p8, out + (size_t)NB * L * HD);
    pb_vtile<<<dim3(NT, 4, NB), 256, 0, stream>>>(v, vt);
    pb_gemm4<<<1024, 256, 0, stream>>>(p8, (const short*)vt, out);
}